// Round 1
// baseline (1097.041 us; speedup 1.0000x reference)
//
#include <hip/hip_runtime.h>
#include <math.h>

// Problem constants (from reference): B=1024, E=64, N=32, D=64
#define NB  1024
#define NE  64
#define NN  32
#define ND  64

// One 256-thread block per (b,e) pair.
// Thread t owns float4-chunk t and t+256 of each 32x64 tile:
//   chunk k -> row n = k>>4, float4-col c = k&15.
__global__ __launch_bounds__(256) void kgcn_agg_kernel(
    const float* __restrict__ self_v,   // [B,E,1,D]
    const float* __restrict__ nbr_v,    // [B,E,N,D]
    const float* __restrict__ nbr_r,    // [B,E,N,D]
    const float* __restrict__ user,     // [B,D]
    const float* __restrict__ W,        // [D, 2D] row-major
    const float* __restrict__ bias,     // [D]
    float* __restrict__ out)            // [B,E,D]
{
    const int pair = blockIdx.x;        // b*E + e
    const int b    = pair >> 6;         // / NE
    const int t    = threadIdx.x;       // 0..255

    __shared__ float4 s_u4[16];         // user[b], 64 floats
    __shared__ float4 s_x4[32];         // concat(self, agg), 128 floats
    __shared__ float  s_scores[NN];
    __shared__ float  s_p[NN];
    __shared__ float4 s_part4[256];     // 16 row-groups x 16 col-groups

    float* s_u    = (float*)s_u4;
    float* s_x    = (float*)s_x4;
    float* s_part = (float*)s_part4;

    // ---- Phase 1: stage user vector + self vector ----
    if (t < 64) {
        s_u[t] = user[b * ND + t];
    } else if (t < 128) {
        s_x[t - 64] = self_v[(size_t)pair * ND + (t - 64)];
    }
    __syncthreads();

    const float4* rel4 = (const float4*)(nbr_r + (size_t)pair * (NN * ND));
    const float4* nv4  = (const float4*)(nbr_v + (size_t)pair * (NN * ND));

    const int col = t & 15;    // float4 column 0..15
    const int rg  = t >> 4;    // row-group 0..15
    const int n_a = rg;        // row of first chunk
    const int n_b = rg + 16;   // row of second chunk

    // ---- Phase 2: scores = user . rel  (and prefetch nbr_v) ----
    float4 u4 = s_u4[col];

    float4 ra = rel4[t];
    float4 rb = rel4[t + 256];
    // prefetch neighbor vectors now: independent of softmax, hides latency
    float4 va = nv4[t];
    float4 vb = nv4[t + 256];

    float pa = ra.x * u4.x + ra.y * u4.y + ra.z * u4.z + ra.w * u4.w;
    float pb = rb.x * u4.x + rb.y * u4.y + rb.z * u4.z + rb.w * u4.w;

    // reduce across the 16 lanes sharing a row (contiguous lane segments)
    #pragma unroll
    for (int off = 8; off > 0; off >>= 1) {
        pa += __shfl_down(pa, off, 16);
        pb += __shfl_down(pb, off, 16);
    }
    if (col == 0) {
        s_scores[n_a] = pa;
        s_scores[n_b] = pb;
    }
    __syncthreads();

    // ---- Phase 3: softmax over 32 neighbors (wave 0, lanes 0..31) ----
    if (t < 32) {
        float v = s_scores[t];
        float m = v;
        #pragma unroll
        for (int off = 16; off > 0; off >>= 1)
            m = fmaxf(m, __shfl_xor(m, off, 32));
        float e = __expf(v - m);
        float s = e;
        #pragma unroll
        for (int off = 16; off > 0; off >>= 1)
            s += __shfl_xor(s, off, 32);
        s_p[t] = e / s;
    }
    __syncthreads();

    // ---- Phase 4: agg[d] = sum_n p[n] * nbr[n][d] ----
    float p_a = s_p[n_a];
    float p_b = s_p[n_b];
    float4 acc;
    acc.x = p_a * va.x + p_b * vb.x;
    acc.y = p_a * va.y + p_b * vb.y;
    acc.z = p_a * va.z + p_b * vb.z;
    acc.w = p_a * va.w + p_b * vb.w;
    s_part4[rg * 16 + col] = acc;   // ds_write_b128, contiguous -> conflict-free
    __syncthreads();

    if (t < 64) {
        float a = 0.f;
        #pragma unroll
        for (int g = 0; g < 16; ++g)
            a += s_part[g * 64 + t];   // lanes consecutive -> conflict-free
        s_x[64 + t] = a;               // concat: agg goes after self
    }
    __syncthreads();

    // ---- Phase 5: out = relu(concat(self,agg) @ W^T + b) ----
    // 4 lanes per output dim; W is 32KB, stays L1/L2 resident across blocks.
    const int dout = t >> 2;   // 0..63
    const int q    = t & 3;    // 0..3, covers k in [q*32, q*32+32)
    const float4* W4 = (const float4*)W;   // [64][32] float4
    float acc2 = 0.f;
    #pragma unroll
    for (int i = 0; i < 8; ++i) {
        float4 w = W4[dout * 32 + q * 8 + i];
        float4 x = s_x4[q * 8 + i];
        acc2 += w.x * x.x + w.y * x.y + w.z * x.z + w.w * x.w;
    }
    acc2 += __shfl_down(acc2, 2, 4);
    acc2 += __shfl_down(acc2, 1, 4);
    if (q == 0) {
        float r = acc2 + bias[dout];
        out[(size_t)pair * ND + dout] = fmaxf(r, 0.f);
    }
}

extern "C" void kernel_launch(void* const* d_in, const int* in_sizes, int n_in,
                              void* d_out, int out_size, void* d_ws, size_t ws_size,
                              hipStream_t stream) {
    const float* self_v = (const float*)d_in[0];
    const float* nbr_v  = (const float*)d_in[1];
    const float* nbr_r  = (const float*)d_in[2];
    const float* user   = (const float*)d_in[3];
    const float* W      = (const float*)d_in[4];
    const float* bias   = (const float*)d_in[5];
    float* out          = (float*)d_out;

    const int n_pairs = NB * NE;  // 65536 blocks
    kgcn_agg_kernel<<<n_pairs, 256, 0, stream>>>(
        self_v, nbr_v, nbr_r, user, W, bias, out);
}